// Round 4
// baseline (4198.252 us; speedup 1.0000x reference)
//
#include <hip/hip_runtime.h>

// Problem constants
#define NROW 16384   // B*H*W
#define KC   2048    // n_codes
#define DIM  512     // embedding dim

typedef __attribute__((ext_vector_type(8))) short  short8;
typedef __attribute__((ext_vector_type(4))) float  floatx4;

// ---------------- helpers ----------------

__device__ __forceinline__ unsigned short f2bf(float f) {
  // round-to-nearest-even fp32 -> bf16 (finite values)
  unsigned int u = __float_as_uint(f);
  u += 0x7fffu + ((u >> 16) & 1u);
  return (unsigned short)(u >> 16);
}

// ---------------- K1: codebook row-normalize -> bf16 + csq ----------------
__global__ void k_cbnorm(const float* __restrict__ emb,
                         unsigned short* __restrict__ cb_bf,
                         float* __restrict__ csq) {
  const int k = blockIdx.x;
  const int t = threadIdx.x;        // 256
  const float* row = emb + (size_t)k * DIM;
  float v0 = row[t], v1 = row[t + 256];
  float ss = v0 * v0 + v1 * v1;
#pragma unroll
  for (int o = 32; o; o >>= 1) ss += __shfl_xor(ss, o, 64);
  __shared__ float red[4];
  if ((t & 63) == 0) red[t >> 6] = ss;
  __syncthreads();
  float tot = red[0] + red[1] + red[2] + red[3];
  float r = 1.0f / fmaxf(sqrtf(tot), 1e-12f);
  cb_bf[(size_t)k * DIM + t]       = f2bf(v0 * r);
  cb_bf[(size_t)k * DIM + t + 256] = f2bf(v1 * r);
  if (t == 0) csq[k] = tot * r * r;   // sum of squares of normalized row (~1)
}

// ---------------- K2: transpose z [B,D,HW] -> flatT [N,D] ----------------
__global__ void k_transpose(const float* __restrict__ z, float* __restrict__ flatT) {
  __shared__ float tile[32][33];
  const int dt = blockIdx.x;   // 0..15  (D/32)
  const int pt = blockIdx.y;   // 0..31  (HW/32)
  const int b  = blockIdx.z;   // 0..15
  const int tx = threadIdx.x & 31;
  const int ty = threadIdx.x >> 5;     // 0..7
  const size_t zb = (size_t)b * (DIM * 1024);
#pragma unroll
  for (int i = 0; i < 4; ++i) {
    int d = dt * 32 + ty + i * 8;
    int p = pt * 32 + tx;
    tile[ty + i * 8][tx] = z[zb + (size_t)d * 1024 + p];
  }
  __syncthreads();
#pragma unroll
  for (int i = 0; i < 4; ++i) {
    int p = pt * 32 + ty + i * 8;
    int d = dt * 32 + tx;
    flatT[(size_t)(b * 1024 + p) * DIM + d] = tile[tx][ty + i * 8];
  }
}

// ---------------- K3: z row norms + bf16 copy ----------------
__global__ void k_rownorm(const float* __restrict__ flatT,
                          float* __restrict__ rnorm,
                          unsigned short* __restrict__ zbf) {
  const int n = blockIdx.x;
  const int t = threadIdx.x;   // 256
  const float* row = flatT + (size_t)n * DIM;
  float v0 = row[t], v1 = row[t + 256];
  float ss = v0 * v0 + v1 * v1;
#pragma unroll
  for (int o = 32; o; o >>= 1) ss += __shfl_xor(ss, o, 64);
  __shared__ float red[4];
  if ((t & 63) == 0) red[t >> 6] = ss;
  __syncthreads();
  float tot = red[0] + red[1] + red[2] + red[3];
  float r = 1.0f / fmaxf(sqrtf(tot), 1e-12f);
  if (t == 0) rnorm[n] = r;
  zbf[(size_t)n * DIM + t]       = f2bf(v0 * r);
  zbf[(size_t)n * DIM + t + 256] = f2bf(v1 * r);
}

// ---------------- K4: bf16 MFMA GEMM -> bf16 logits t = 2*S - csq ----------------
// 128x128 tile, BK=64, 4 waves of 64x64, 16x16x32 MFMA, XOR-swizzled LDS.
// Output: bf16 t for row n stored in the first 4KB of dp row n's 8KB slot
// (row stride 4096 ushorts); halves S write + softmax read traffic.
__global__ __launch_bounds__(256) void k_gemm(const unsigned short* __restrict__ A,
                                              const unsigned short* __restrict__ Bm,
                                              const float* __restrict__ csq,
                                              unsigned short* __restrict__ T16) {
  __shared__ alignas(16) unsigned short smA[128 * 64];
  __shared__ alignas(16) unsigned short smB[128 * 64];
  const int tid  = threadIdx.x;
  const int wid  = tid >> 6;
  const int lane = tid & 63;
  const int m0 = blockIdx.x * 128;
  const int n0 = blockIdx.y * 128;
  const int wm = (wid >> 1) * 64;
  const int wn = (wid & 1) * 64;

  floatx4 acc[4][4];
  const floatx4 z4 = {0.f, 0.f, 0.f, 0.f};
#pragma unroll
  for (int mi = 0; mi < 4; ++mi)
#pragma unroll
    for (int ni = 0; ni < 4; ++ni) acc[mi][ni] = z4;

  const int srow_l = tid >> 3;  // +i*32 per staging issue
  const int spb    = tid & 7;

  for (int kt = 0; kt < 8; ++kt) {
    const int kbase = kt * 64;
    // stage A and B tiles (manual vectorized staging, swizzled layout:
    // physical 16B-block pb holds logical block lb = pb ^ (row & 7))
#pragma unroll
    for (int i = 0; i < 4; ++i) {
      int row = i * 32 + srow_l;
      int lb  = spb ^ (row & 7);
      const short8 va = *(const short8*)(A  + (size_t)(m0 + row) * DIM + kbase + lb * 8);
      const short8 vb = *(const short8*)(Bm + (size_t)(n0 + row) * DIM + kbase + lb * 8);
      *(short8*)&smA[i * 2048 + tid * 8] = va;
      *(short8*)&smB[i * 2048 + tid * 8] = vb;
    }
    __syncthreads();
#pragma unroll
    for (int kk = 0; kk < 2; ++kk) {
      const int q   = lane >> 4;
      const int mr  = lane & 15;
      const int lbq = kk * 4 + q;   // logical 8-elem block index in row
      short8 af[4], bfr[4];
#pragma unroll
      for (int mi = 0; mi < 4; ++mi) {
        int row = wm + mi * 16 + mr;
        int pb  = lbq ^ (row & 7);
        af[mi] = *(const short8*)&smA[row * 64 + pb * 8];
      }
#pragma unroll
      for (int ni = 0; ni < 4; ++ni) {
        int row = wn + ni * 16 + mr;
        int pb  = lbq ^ (row & 7);
        bfr[ni] = *(const short8*)&smB[row * 64 + pb * 8];
      }
#pragma unroll
      for (int mi = 0; mi < 4; ++mi)
#pragma unroll
        for (int ni = 0; ni < 4; ++ni)
          acc[mi][ni] = __builtin_amdgcn_mfma_f32_16x16x32_bf16(af[mi], bfr[ni], acc[mi][ni], 0, 0, 0);
    }
    __syncthreads();
  }

  // epilogue: C/D layout col = lane&15, row = (lane>>4)*4 + reg; t = 2S - csq -> bf16
  const int col = lane & 15;
  const int rq  = (lane >> 4) * 4;
  float csqv[4];
#pragma unroll
  for (int ni = 0; ni < 4; ++ni) csqv[ni] = csq[n0 + wn + ni * 16 + col];
#pragma unroll
  for (int mi = 0; mi < 4; ++mi)
#pragma unroll
    for (int r = 0; r < 4; ++r) {
      size_t rowoff = (size_t)(m0 + wm + mi * 16 + rq + r) * 4096;  // 8KB slot
#pragma unroll
      for (int ni = 0; ni < 4; ++ni)
        T16[rowoff + n0 + wn + ni * 16 + col] = f2bf(2.0f * acc[mi][ni][r] - csqv[ni]);
    }
}

// ---------------- K5: softmax from bf16 logits (in-slot) + argmin candidates ----------------
// t <= ~1.03 bounded (unit vectors) => fixed reference: dp = exp(t-1)/sum == softmax(t).
// Margin must cover bf16-dot (~1e-2) + bf16-logit-store (~2.2e-3) per side => 0.025.
#define EXP_MARGIN 0.97531f   // exp(-0.025)

__global__ void k_softmax(float* dp,
                          int* __restrict__ cand_cnt, int* __restrict__ cand_list) {
  const int n = blockIdx.x;
  const int t = threadIdx.x;  // 256
  const int lane = t & 63, wid = t >> 6;
  float* row = dp + (size_t)n * KC;                      // 8KB slot, fp32 view
  const unsigned short* srow = (const unsigned short*)row;  // bf16 t in first 4KB
  short8 v = *(const short8*)&srow[t * 8];               // k = t*8 .. t*8+7
  float ev[8];
  float mx = 0.f, sum = 0.f;
#pragma unroll
  for (int j = 0; j < 8; ++j) {
    float tv = __uint_as_float(((unsigned)(unsigned short)v[j]) << 16);
    ev[j] = __expf(tv - 1.0f);
    mx = fmaxf(mx, ev[j]);
    sum += ev[j];
  }
#pragma unroll
  for (int o = 32; o; o >>= 1) {
    mx  = fmaxf(mx, __shfl_xor(mx, o, 64));
    sum += __shfl_xor(sum, o, 64);
  }
  __shared__ float redm[4], reds[4];
  __shared__ int s_cnt;
  if (t == 0) s_cnt = 0;
  if (lane == 0) { redm[wid] = mx; reds[wid] = sum; }
  __syncthreads();   // also orders: all bf16 loads complete before any fp32 store
  const float EMX = fmaxf(fmaxf(redm[0], redm[1]), fmaxf(redm[2], redm[3]));
  const float inv = 1.0f / (reds[0] + reds[1] + reds[2] + reds[3]);
  const float thr = EMX * EXP_MARGIN;
#pragma unroll
  for (int j = 0; j < 8; ++j) {
    if (ev[j] >= thr) {
      int p = atomicAdd(&s_cnt, 1);
      if (p < 16) cand_list[n * 16 + p] = t * 8 + j;
    }
  }
  floatx4 w0, w1;
#pragma unroll
  for (int j = 0; j < 4; ++j) { w0[j] = ev[j] * inv; w1[j] = ev[j + 4] * inv; }
  *(floatx4*)&row[t * 8]     = w0;
  *(floatx4*)&row[t * 8 + 4] = w1;
  __syncthreads();
  if (t == 0) cand_cnt[n] = (s_cnt > 16) ? -1 : s_cnt;
}

// ---------------- K6: exact fp64 argmin among candidates ----------------
__global__ void k_fixup(const float* __restrict__ flatT, const float* __restrict__ emb,
                        const int* __restrict__ cand_cnt, const int* __restrict__ cand_list,
                        int* __restrict__ idx) {
  const int n = blockIdx.x;
  const int l = threadIdx.x;  // 64
  const int c = cand_cnt[n];
  if (c == 1) {
    if (l == 0) idx[n] = cand_list[n * 16];
    return;
  }
  const float* zr = flatT + (size_t)n * DIM;
  double zs = 0.0;
  for (int d = l; d < DIM; d += 64) { double v = zr[d]; zs += v * v; }
#pragma unroll
  for (int o = 32; o; o >>= 1) zs += __shfl_xor(zs, o, 64);
  double zn = fmax(sqrt(zs), 1e-12);
  double best = 1e300;
  int bestk = 0x7fffffff;
  const int m = (c < 0) ? KC : c;
  for (int ci = 0; ci < m; ++ci) {
    int k = (c < 0) ? ci : cand_list[n * 16 + ci];
    const float* er = emb + (size_t)k * DIM;
    double cs = 0.0, dot = 0.0;
    for (int d = l; d < DIM; d += 64) {
      double e = er[d], zv = zr[d];
      cs += e * e; dot += zv * e;
    }
#pragma unroll
    for (int o = 32; o; o >>= 1) { cs += __shfl_xor(cs, o, 64); dot += __shfl_xor(dot, o, 64); }
    double cn = fmax(sqrt(cs), 1e-12);
    double score = cs / (cn * cn) - 2.0 * dot / (zn * cn);  // distance minus row-const zsq
    if (score < best || (score == best && k < bestk)) { best = score; bestk = k; }
  }
  if (l == 0) idx[n] = bestk;
}

// ---------------- K7: commitment-loss partials + EMA stats (atomics) ----------------
__global__ void k_stats(const float* __restrict__ flatT, const float* __restrict__ rnorm,
                        const int* __restrict__ idx, float* __restrict__ enc_sum,
                        float* __restrict__ n_total, double* __restrict__ cl_part) {
  const int n = blockIdx.x;
  const int t = threadIdx.x;  // 256
  const int j = idx[n];
  const float rn = rnorm[n], rj = rnorm[j];
  const float* zr  = flatT + (size_t)n * DIM;
  const float* zjr = flatT + (size_t)j * DIM;
  double cl = 0.0;
#pragma unroll
  for (int i = 0; i < 2; ++i) {
    int d = t + i * 256;
    float zv = zr[d] * rn;
    float evv = zjr[d] * rj;
    float df = zv - evv;
    cl += (double)df * (double)df;
    atomicAdd(&enc_sum[(size_t)j * DIM + d], zv);
  }
#pragma unroll
  for (int o = 32; o; o >>= 1) cl += __shfl_xor(cl, o, 64);
  __shared__ double red[4];
  if ((t & 63) == 0) red[t >> 6] = cl;
  __syncthreads();
  if (t == 0) {
    cl_part[n] = red[0] + red[1] + red[2] + red[3];
    atomicAdd(&n_total[j], 1.0f);
  }
}

// ---------------- K8: fused tail — z_avg_new, N_new, embeddings_new, |.| partials ----
__global__ void k_tail(const float* __restrict__ za, const float* __restrict__ es,
                       const float* __restrict__ Nb, const float* __restrict__ ntot,
                       float* __restrict__ out_zav, float* __restrict__ outN,
                       float* __restrict__ out_emb, double* __restrict__ cbs_part) {
  const int k = blockIdx.x;   // 2048
  const int t = threadIdx.x;  // 256
  const int lane = t & 63, wid = t >> 6;
  float s = 0.f;
#pragma unroll
  for (int i = 0; i < 8; ++i) {
    int kk = t + i * 256;
    s += 0.99f * Nb[kk] + 0.01f * ntot[kk];
  }
#pragma unroll
  for (int o = 32; o; o >>= 1) s += __shfl_xor(s, o, 64);
  __shared__ float redn[4];
  if (lane == 0) redn[wid] = s;
  __syncthreads();
  const float nv = redn[0] + redn[1] + redn[2] + redn[3];
  const float Nn = 0.99f * Nb[k] + 0.01f * ntot[k];
  if (t == 0) outN[k] = Nn;
  const float w = (Nn + 1e-5f) / (nv + 0.02048f) * nv;
  double a = 0.0;
#pragma unroll
  for (int i = 0; i < 2; ++i) {
    size_t gi = (size_t)k * DIM + t + i * 256;
    float zv = 0.99f * za[gi] + 0.01f * es[gi];
    out_zav[gi] = zv;
    float e = zv / w;
    out_emb[gi] = e;
    a += (double)fabsf(e);
  }
#pragma unroll
  for (int o = 32; o; o >>= 1) a += __shfl_xor(a, o, 64);
  __shared__ double red[4];
  if (lane == 0) red[wid] = a;
  __syncthreads();
  if (t == 0) cbs_part[k] = red[0] + red[1] + red[2] + red[3];
}

// ---------------- K9: q gather + (extra block) final scalar reductions ----------------
__global__ void k_q(const float* __restrict__ flatT, const float* __restrict__ rnorm,
                    const int* __restrict__ idx, float* __restrict__ out,
                    const double* __restrict__ cl_part, const double* __restrict__ cbs_part) {
  if (blockIdx.x == 32768) {
    const int t = threadIdx.x;  // 256
    double cl = 0.0, cb = 0.0;
    for (int i = t; i < NROW; i += 256) cl += cl_part[i];
    for (int i = t; i < KC; i += 256) cb += cbs_part[i];
#pragma unroll
    for (int o = 32; o; o >>= 1) { cl += __shfl_xor(cl, o, 64); cb += __shfl_xor(cb, o, 64); }
    __shared__ double redc[4], redb[4];
    if ((t & 63) == 0) { redc[t >> 6] = cl; redb[t >> 6] = cb; }
    __syncthreads();
    if (t == 0) {
      double clm = (redc[0] + redc[1] + redc[2] + redc[3]) / 8388608.0;  // N*D
      double cbs = redb[0] + redb[1] + redb[2] + redb[3];
      out[41943040] = (float)clm;          // commitment_loss
      out[41943041] = (float)(0.25 * clm); // loss = BETA * commitment_loss
      out[41943042] = (float)cbs;          // codebook_sum
    }
    return;
  }
  const int o = blockIdx.x * 256 + threadIdx.x;
  const int b = o >> 19;            // D*H*W = 2^19
  const int d = (o >> 10) & 511;
  const int p = o & 1023;
  const int j = idx[(b << 10) + p];
  out[o] = flatT[(size_t)j * DIM + d] * rnorm[j];
}

// ---------------- launcher ----------------
extern "C" void kernel_launch(void* const* d_in, const int* in_sizes, int n_in,
                              void* d_out, int out_size, void* d_ws, size_t ws_size,
                              hipStream_t stream) {
  const float* z   = (const float*)d_in[0];
  const float* emb = (const float*)d_in[1];
  const float* Nb  = (const float*)d_in[2];
  const float* za  = (const float*)d_in[3];
  float* out = (float*)d_out;
  char*  ws  = (char*)d_ws;

  // workspace layout (bytes)
  float*          flatT     = (float*)(ws + 0);          // 33554432
  unsigned short* cb_bf     = (unsigned short*)(ws + 33554432); // 2097152
  float*          csq       = (float*)(ws + 35651584);   // 8192
  float*          rnorm     = (float*)(ws + 35659776);   // 65536
  int*            idx       = (int*)(ws + 35725312);     // 65536
  int*            cand_cnt  = (int*)(ws + 35790848);     // 65536
  int*            cand_list = (int*)(ws + 35856384);     // 1048576
  double*         cl_part   = (double*)(ws + 36904960);  // 131072
  double*         cbs_part  = (double*)(ws + 37036032);  // 32768 (2048 used)
  float*          enc_sum   = (float*)(ws + 37068800);   // 4194304 (zeroed)
  float*          n_total   = (float*)(ws + 41263104);   // 8192    (zeroed)

  // d_out regions (floats): q[0..8388608), dp[8388608..41943040),
  // scalars[41943040..3), emb_new[41943043), N_new[42991619), z_avg_new[42993667)
  unsigned short* z_bf  = (unsigned short*)out;   // q region reused as bf16 scratch
  float* dpS      = out + 8388608;                // dp rows; bf16 logits in-slot
  unsigned short* S16 = (unsigned short*)dpS;     // row stride 4096 ushorts (8KB)
  float* out_emb  = out + 41943043;
  float* out_N    = out + 42991619;
  float* out_zav  = out + 42993667;

  hipMemsetAsync(ws + 37068800, 0, 4202496, stream);   // enc_sum + n_total

  k_cbnorm   <<<KC, 256, 0, stream>>>(emb, cb_bf, csq);
  k_transpose<<<dim3(16, 32, 16), 256, 0, stream>>>(z, flatT);
  k_rownorm  <<<NROW, 256, 0, stream>>>(flatT, rnorm, z_bf);
  k_gemm     <<<dim3(NROW / 128, KC / 128), 256, 0, stream>>>(z_bf, cb_bf, csq, S16);
  k_softmax  <<<NROW, 256, 0, stream>>>(dpS, cand_cnt, cand_list);
  k_fixup    <<<NROW, 64, 0, stream>>>(flatT, emb, cand_cnt, cand_list, idx);
  k_stats    <<<NROW, 256, 0, stream>>>(flatT, rnorm, idx, enc_sum, n_total, cl_part);
  k_tail     <<<KC, 256, 0, stream>>>(za, enc_sum, Nb, n_total, out_zav, out_N, out_emb, cbs_part);
  k_q        <<<32769, 256, 0, stream>>>(flatT, rnorm, idx, out, cl_part, cbs_part);
}

// Round 5
// 407.992 us; speedup vs baseline: 10.2900x; 10.2900x over previous
//
#include <hip/hip_runtime.h>

// Problem constants
#define NROW 16384   // B*H*W
#define KC   2048    // n_codes
#define DIM  512     // embedding dim

typedef __attribute__((ext_vector_type(8))) short  short8;
typedef __attribute__((ext_vector_type(4))) float  floatx4;

// ---------------- helpers ----------------

__device__ __forceinline__ unsigned short f2bf(float f) {
  // round-to-nearest-even fp32 -> bf16 (finite values)
  unsigned int u = __float_as_uint(f);
  u += 0x7fffu + ((u >> 16) & 1u);
  return (unsigned short)(u >> 16);
}

// ---------------- K1: codebook row-normalize -> bf16 + csq ----------------
__global__ void k_cbnorm(const float* __restrict__ emb,
                         unsigned short* __restrict__ cb_bf,
                         float* __restrict__ csq) {
  const int k = blockIdx.x;
  const int t = threadIdx.x;        // 256
  const float* row = emb + (size_t)k * DIM;
  float v0 = row[t], v1 = row[t + 256];
  float ss = v0 * v0 + v1 * v1;
#pragma unroll
  for (int o = 32; o; o >>= 1) ss += __shfl_xor(ss, o, 64);
  __shared__ float red[4];
  if ((t & 63) == 0) red[t >> 6] = ss;
  __syncthreads();
  float tot = red[0] + red[1] + red[2] + red[3];
  float r = 1.0f / fmaxf(sqrtf(tot), 1e-12f);
  cb_bf[(size_t)k * DIM + t]       = f2bf(v0 * r);
  cb_bf[(size_t)k * DIM + t + 256] = f2bf(v1 * r);
  if (t == 0) csq[k] = tot * r * r;   // sum of squares of normalized row (~1)
}

// ---------------- K2: transpose z [B,D,HW] -> flatT [N,D] ----------------
__global__ void k_transpose(const float* __restrict__ z, float* __restrict__ flatT) {
  __shared__ float tile[32][33];
  const int dt = blockIdx.x;   // 0..15  (D/32)
  const int pt = blockIdx.y;   // 0..31  (HW/32)
  const int b  = blockIdx.z;   // 0..15
  const int tx = threadIdx.x & 31;
  const int ty = threadIdx.x >> 5;     // 0..7
  const size_t zb = (size_t)b * (DIM * 1024);
#pragma unroll
  for (int i = 0; i < 4; ++i) {
    int d = dt * 32 + ty + i * 8;
    int p = pt * 32 + tx;
    tile[ty + i * 8][tx] = z[zb + (size_t)d * 1024 + p];
  }
  __syncthreads();
#pragma unroll
  for (int i = 0; i < 4; ++i) {
    int p = pt * 32 + ty + i * 8;
    int d = dt * 32 + tx;
    flatT[(size_t)(b * 1024 + p) * DIM + d] = tile[tx][ty + i * 8];
  }
}

// ---------------- K3: z row norms + bf16 copy ----------------
__global__ void k_rownorm(const float* __restrict__ flatT,
                          float* __restrict__ rnorm,
                          unsigned short* __restrict__ zbf) {
  const int n = blockIdx.x;
  const int t = threadIdx.x;   // 256
  const float* row = flatT + (size_t)n * DIM;
  float v0 = row[t], v1 = row[t + 256];
  float ss = v0 * v0 + v1 * v1;
#pragma unroll
  for (int o = 32; o; o >>= 1) ss += __shfl_xor(ss, o, 64);
  __shared__ float red[4];
  if ((t & 63) == 0) red[t >> 6] = ss;
  __syncthreads();
  float tot = red[0] + red[1] + red[2] + red[3];
  float r = 1.0f / fmaxf(sqrtf(tot), 1e-12f);
  if (t == 0) rnorm[n] = r;
  zbf[(size_t)n * DIM + t]       = f2bf(v0 * r);
  zbf[(size_t)n * DIM + t + 256] = f2bf(v1 * r);
}

// ---------------- K4: bf16 MFMA GEMM -> bf16 logits t = 2*S - csq ----------------
// 128x128 tile, BK=64, 4 waves of 64x64, 16x16x32 MFMA, XOR-swizzled LDS.
// Output: bf16 t for row n stored in the first 4KB of dp row n's 8KB slot
// (row stride 4096 ushorts); halves S write + softmax read traffic.
__global__ __launch_bounds__(256) void k_gemm(const unsigned short* __restrict__ A,
                                              const unsigned short* __restrict__ Bm,
                                              const float* __restrict__ csq,
                                              unsigned short* __restrict__ T16) {
  __shared__ alignas(16) unsigned short smA[128 * 64];
  __shared__ alignas(16) unsigned short smB[128 * 64];
  const int tid  = threadIdx.x;
  const int wid  = tid >> 6;
  const int lane = tid & 63;
  const int m0 = blockIdx.x * 128;
  const int n0 = blockIdx.y * 128;
  const int wm = (wid >> 1) * 64;
  const int wn = (wid & 1) * 64;

  floatx4 acc[4][4];
  const floatx4 z4 = {0.f, 0.f, 0.f, 0.f};
#pragma unroll
  for (int mi = 0; mi < 4; ++mi)
#pragma unroll
    for (int ni = 0; ni < 4; ++ni) acc[mi][ni] = z4;

  const int srow_l = tid >> 3;  // +i*32 per staging issue
  const int spb    = tid & 7;

  for (int kt = 0; kt < 8; ++kt) {
    const int kbase = kt * 64;
    // stage A and B tiles (manual vectorized staging, swizzled layout:
    // physical 16B-block pb holds logical block lb = pb ^ (row & 7))
#pragma unroll
    for (int i = 0; i < 4; ++i) {
      int row = i * 32 + srow_l;
      int lb  = spb ^ (row & 7);
      const short8 va = *(const short8*)(A  + (size_t)(m0 + row) * DIM + kbase + lb * 8);
      const short8 vb = *(const short8*)(Bm + (size_t)(n0 + row) * DIM + kbase + lb * 8);
      *(short8*)&smA[i * 2048 + tid * 8] = va;
      *(short8*)&smB[i * 2048 + tid * 8] = vb;
    }
    __syncthreads();
#pragma unroll
    for (int kk = 0; kk < 2; ++kk) {
      const int q   = lane >> 4;
      const int mr  = lane & 15;
      const int lbq = kk * 4 + q;   // logical 8-elem block index in row
      short8 af[4], bfr[4];
#pragma unroll
      for (int mi = 0; mi < 4; ++mi) {
        int row = wm + mi * 16 + mr;
        int pb  = lbq ^ (row & 7);
        af[mi] = *(const short8*)&smA[row * 64 + pb * 8];
      }
#pragma unroll
      for (int ni = 0; ni < 4; ++ni) {
        int row = wn + ni * 16 + mr;
        int pb  = lbq ^ (row & 7);
        bfr[ni] = *(const short8*)&smB[row * 64 + pb * 8];
      }
#pragma unroll
      for (int mi = 0; mi < 4; ++mi)
#pragma unroll
        for (int ni = 0; ni < 4; ++ni)
          acc[mi][ni] = __builtin_amdgcn_mfma_f32_16x16x32_bf16(af[mi], bfr[ni], acc[mi][ni], 0, 0, 0);
    }
    __syncthreads();
  }

  // epilogue: C/D layout col = lane&15, row = (lane>>4)*4 + reg; t = 2S - csq -> bf16
  const int col = lane & 15;
  const int rq  = (lane >> 4) * 4;
  float csqv[4];
#pragma unroll
  for (int ni = 0; ni < 4; ++ni) csqv[ni] = csq[n0 + wn + ni * 16 + col];
#pragma unroll
  for (int mi = 0; mi < 4; ++mi)
#pragma unroll
    for (int r = 0; r < 4; ++r) {
      size_t rowoff = (size_t)(m0 + wm + mi * 16 + rq + r) * 4096;  // 8KB slot
#pragma unroll
      for (int ni = 0; ni < 4; ++ni)
        T16[rowoff + n0 + wn + ni * 16 + col] = f2bf(2.0f * acc[mi][ni][r] - csqv[ni]);
    }
}

// ---------------- K5: softmax from bf16 logits (in-slot) + argmin candidates ----------------
// t <= ~1.03 bounded (unit vectors) => fixed reference: dp = exp(t-1)/sum == softmax(t).
// Margin must cover bf16-dot (~1e-2) + bf16-logit-store (~4e-3) per side => 0.025.
#define EXP_MARGIN 0.97531f   // exp(-0.025)

__global__ void k_softmax(float* dp,
                          int* __restrict__ cand_cnt, int* __restrict__ cand_list) {
  const int n = blockIdx.x;
  const int t = threadIdx.x;  // 256
  const int lane = t & 63, wid = t >> 6;
  float* row = dp + (size_t)n * KC;                      // 8KB slot, fp32 view
  const unsigned short* srow = (const unsigned short*)row;  // bf16 t in first 4KB
  short8 v = *(const short8*)&srow[t * 8];               // k = t*8 .. t*8+7
  float ev[8];
  float mx = 0.f, sum = 0.f;
#pragma unroll
  for (int j = 0; j < 8; ++j) {
    float tv = __uint_as_float(((unsigned)(unsigned short)v[j]) << 16);
    ev[j] = __expf(tv - 1.0f);
    mx = fmaxf(mx, ev[j]);
    sum += ev[j];
  }
#pragma unroll
  for (int o = 32; o; o >>= 1) {
    mx  = fmaxf(mx, __shfl_xor(mx, o, 64));
    sum += __shfl_xor(sum, o, 64);
  }
  __shared__ float redm[4], reds[4];
  __shared__ int s_cnt;
  if (t == 0) s_cnt = 0;
  if (lane == 0) { redm[wid] = mx; reds[wid] = sum; }
  __syncthreads();   // also orders: all bf16 loads complete before any fp32 store
  const float EMX = fmaxf(fmaxf(redm[0], redm[1]), fmaxf(redm[2], redm[3]));
  const float inv = 1.0f / (reds[0] + reds[1] + reds[2] + reds[3]);
  const float thr = EMX * EXP_MARGIN;
#pragma unroll
  for (int j = 0; j < 8; ++j) {
    if (ev[j] >= thr) {
      int p = atomicAdd(&s_cnt, 1);
      if (p < 16) cand_list[n * 16 + p] = t * 8 + j;
    }
  }
  floatx4 w0, w1;
#pragma unroll
  for (int j = 0; j < 4; ++j) { w0[j] = ev[j] * inv; w1[j] = ev[j + 4] * inv; }
  *(floatx4*)&row[t * 8]     = w0;
  *(floatx4*)&row[t * 8 + 4] = w1;
  __syncthreads();
  if (t == 0) cand_cnt[n] = (s_cnt > 16) ? -1 : s_cnt;
}

// ---------------- K6: exact fp64 argmin among candidates (wave-parallel) ----------------
// c in [2,16]: candidates from cand_list. c == -1 (cap overflow): re-derive the
// FULL margin set from the dp row (dp is monotone in t, same margin in exp domain)
// into a 256-slot LDS list; full-KC scan only past 256 (statistically unreachable).
// Per-candidate fp64 reduction tree identical to the serial version -> same winners.
__global__ void k_fixup(const float* __restrict__ flatT, const float* __restrict__ emb,
                        const float* __restrict__ dp,
                        const int* __restrict__ cand_cnt, const int* __restrict__ cand_list,
                        int* __restrict__ idx) {
  const int n = blockIdx.x;
  const int t = threadIdx.x;      // 256
  const int lane = t & 63, w = t >> 6;
  const int c = cand_cnt[n];
  if (c == 1) {
    if (t == 0) idx[n] = cand_list[n * 16];
    return;
  }

  __shared__ int    s_cand[256];
  __shared__ int    s_m;
  __shared__ int    s_cnt2;
  __shared__ float  redf[4];
  __shared__ double s_best[4];
  __shared__ int    s_bestk[4];

  if (c > 1) {
    if (t < c) s_cand[t] = cand_list[n * 16 + t];
    if (t == 0) s_m = c;
  } else {
    // cap overflow: rebuild candidate set from dp (uncapped, up to 256)
    const float* row = dp + (size_t)n * KC;
    float v[8];
    float mx = 0.f;
#pragma unroll
    for (int j = 0; j < 8; ++j) { v[j] = row[t * 8 + j]; mx = fmaxf(mx, v[j]); }
#pragma unroll
    for (int o = 32; o; o >>= 1) mx = fmaxf(mx, __shfl_xor(mx, o, 64));
    if (lane == 0) redf[w] = mx;
    if (t == 0) s_cnt2 = 0;
    __syncthreads();
    const float thr = fmaxf(fmaxf(redf[0], redf[1]), fmaxf(redf[2], redf[3])) * EXP_MARGIN;
#pragma unroll
    for (int j = 0; j < 8; ++j) {
      if (v[j] >= thr) {
        int p = atomicAdd(&s_cnt2, 1);
        if (p < 256) s_cand[p] = t * 8 + j;
      }
    }
    __syncthreads();
    if (t == 0) s_m = (s_cnt2 > 256) ? -1 : s_cnt2;
  }
  __syncthreads();
  const int m = s_m;

  // z row cached in registers, reused across candidates
  const float* zr = flatT + (size_t)n * DIM;
  float zf[8];
#pragma unroll
  for (int u = 0; u < 8; ++u) zf[u] = zr[lane + 64 * u];
  double zs = 0.0;
#pragma unroll
  for (int u = 0; u < 8; ++u) { double zv = zf[u]; zs += zv * zv; }
#pragma unroll
  for (int o = 32; o; o >>= 1) zs += __shfl_xor(zs, o, 64);
  const double zn = fmax(sqrt(zs), 1e-12);

  double best = 1e300;
  int bestk = 0x7fffffff;
  const int M = (m < 0) ? KC : m;
  for (int ci = w; ci < M; ci += 4) {       // wave-parallel over candidates
    const int k = (m < 0) ? ci : s_cand[ci];
    const float* er = emb + (size_t)k * DIM;
    float ef[8];
#pragma unroll
    for (int u = 0; u < 8; ++u) ef[u] = er[lane + 64 * u];   // 8 independent loads
    double cs = 0.0, dot = 0.0;
#pragma unroll
    for (int u = 0; u < 8; ++u) { double e = ef[u]; double zv = zf[u]; cs += e * e; dot += zv * e; }
#pragma unroll
    for (int o = 32; o; o >>= 1) { cs += __shfl_xor(cs, o, 64); dot += __shfl_xor(dot, o, 64); }
    double cn = fmax(sqrt(cs), 1e-12);
    double score = cs / (cn * cn) - 2.0 * dot / (zn * cn);  // distance minus row-const zsq
    if (score < best || (score == best && k < bestk)) { best = score; bestk = k; }
  }
  if (lane == 0) { s_best[w] = best; s_bestk[w] = bestk; }
  __syncthreads();
  if (t == 0) {
    double b = s_best[0]; int bk = s_bestk[0];
#pragma unroll
    for (int i = 1; i < 4; ++i)
      if (s_best[i] < b || (s_best[i] == b && s_bestk[i] < bk)) { b = s_best[i]; bk = s_bestk[i]; }
    idx[n] = bk;
  }
}

// ---------------- K7: commitment-loss partials + EMA stats (atomics) ----------------
__global__ void k_stats(const float* __restrict__ flatT, const float* __restrict__ rnorm,
                        const int* __restrict__ idx, float* __restrict__ enc_sum,
                        float* __restrict__ n_total, double* __restrict__ cl_part) {
  const int n = blockIdx.x;
  const int t = threadIdx.x;  // 256
  const int j = idx[n];
  const float rn = rnorm[n], rj = rnorm[j];
  const float* zr  = flatT + (size_t)n * DIM;
  const float* zjr = flatT + (size_t)j * DIM;
  double cl = 0.0;
#pragma unroll
  for (int i = 0; i < 2; ++i) {
    int d = t + i * 256;
    float zv = zr[d] * rn;
    float evv = zjr[d] * rj;
    float df = zv - evv;
    cl += (double)df * (double)df;
    atomicAdd(&enc_sum[(size_t)j * DIM + d], zv);
  }
#pragma unroll
  for (int o = 32; o; o >>= 1) cl += __shfl_xor(cl, o, 64);
  __shared__ double red[4];
  if ((t & 63) == 0) red[t >> 6] = cl;
  __syncthreads();
  if (t == 0) {
    cl_part[n] = red[0] + red[1] + red[2] + red[3];
    atomicAdd(&n_total[j], 1.0f);
  }
}

// ---------------- K8: fused tail — z_avg_new, N_new, embeddings_new, |.| partials ----
__global__ void k_tail(const float* __restrict__ za, const float* __restrict__ es,
                       const float* __restrict__ Nb, const float* __restrict__ ntot,
                       float* __restrict__ out_zav, float* __restrict__ outN,
                       float* __restrict__ out_emb, double* __restrict__ cbs_part) {
  const int k = blockIdx.x;   // 2048
  const int t = threadIdx.x;  // 256
  const int lane = t & 63, wid = t >> 6;
  float s = 0.f;
#pragma unroll
  for (int i = 0; i < 8; ++i) {
    int kk = t + i * 256;
    s += 0.99f * Nb[kk] + 0.01f * ntot[kk];
  }
#pragma unroll
  for (int o = 32; o; o >>= 1) s += __shfl_xor(s, o, 64);
  __shared__ float redn[4];
  if (lane == 0) redn[wid] = s;
  __syncthreads();
  const float nv = redn[0] + redn[1] + redn[2] + redn[3];
  const float Nn = 0.99f * Nb[k] + 0.01f * ntot[k];
  if (t == 0) outN[k] = Nn;
  const float w = (Nn + 1e-5f) / (nv + 0.02048f) * nv;
  double a = 0.0;
#pragma unroll
  for (int i = 0; i < 2; ++i) {
    size_t gi = (size_t)k * DIM + t + i * 256;
    float zv = 0.99f * za[gi] + 0.01f * es[gi];
    out_zav[gi] = zv;
    float e = zv / w;
    out_emb[gi] = e;
    a += (double)fabsf(e);
  }
#pragma unroll
  for (int o = 32; o; o >>= 1) a += __shfl_xor(a, o, 64);
  __shared__ double red[4];
  if (lane == 0) red[wid] = a;
  __syncthreads();
  if (t == 0) cbs_part[k] = red[0] + red[1] + red[2] + red[3];
}

// ---------------- K9: q gather + (extra block) final scalar reductions ----------------
__global__ void k_q(const float* __restrict__ flatT, const float* __restrict__ rnorm,
                    const int* __restrict__ idx, float* __restrict__ out,
                    const double* __restrict__ cl_part, const double* __restrict__ cbs_part) {
  if (blockIdx.x == 32768) {
    const int t = threadIdx.x;  // 256
    double cl = 0.0, cb = 0.0;
    for (int i = t; i < NROW; i += 256) cl += cl_part[i];
    for (int i = t; i < KC; i += 256) cb += cbs_part[i];
#pragma unroll
    for (int o = 32; o; o >>= 1) { cl += __shfl_xor(cl, o, 64); cb += __shfl_xor(cb, o, 64); }
    __shared__ double redc[4], redb[4];
    if ((t & 63) == 0) { redc[t >> 6] = cl; redb[t >> 6] = cb; }
    __syncthreads();
    if (t == 0) {
      double clm = (redc[0] + redc[1] + redc[2] + redc[3]) / 8388608.0;  // N*D
      double cbs = redb[0] + redb[1] + redb[2] + redb[3];
      out[41943040] = (float)clm;          // commitment_loss
      out[41943041] = (float)(0.25 * clm); // loss = BETA * commitment_loss
      out[41943042] = (float)cbs;          // codebook_sum
    }
    return;
  }
  const int o = blockIdx.x * 256 + threadIdx.x;
  const int b = o >> 19;            // D*H*W = 2^19
  const int d = (o >> 10) & 511;
  const int p = o & 1023;
  const int j = idx[(b << 10) + p];
  out[o] = flatT[(size_t)j * DIM + d] * rnorm[j];
}

// ---------------- launcher ----------------
extern "C" void kernel_launch(void* const* d_in, const int* in_sizes, int n_in,
                              void* d_out, int out_size, void* d_ws, size_t ws_size,
                              hipStream_t stream) {
  const float* z   = (const float*)d_in[0];
  const float* emb = (const float*)d_in[1];
  const float* Nb  = (const float*)d_in[2];
  const float* za  = (const float*)d_in[3];
  float* out = (float*)d_out;
  char*  ws  = (char*)d_ws;

  // workspace layout (bytes)
  float*          flatT     = (float*)(ws + 0);          // 33554432
  unsigned short* cb_bf     = (unsigned short*)(ws + 33554432); // 2097152
  float*          csq       = (float*)(ws + 35651584);   // 8192
  float*          rnorm     = (float*)(ws + 35659776);   // 65536
  int*            idx       = (int*)(ws + 35725312);     // 65536
  int*            cand_cnt  = (int*)(ws + 35790848);     // 65536
  int*            cand_list = (int*)(ws + 35856384);     // 1048576
  double*         cl_part   = (double*)(ws + 36904960);  // 131072
  double*         cbs_part  = (double*)(ws + 37036032);  // 32768 (2048 used)
  float*          enc_sum   = (float*)(ws + 37068800);   // 4194304 (zeroed)
  float*          n_total   = (float*)(ws + 41263104);   // 8192    (zeroed)

  // d_out regions (floats): q[0..8388608), dp[8388608..41943040),
  // scalars[41943040..3), emb_new[41943043), N_new[42991619), z_avg_new[42993667)
  unsigned short* z_bf  = (unsigned short*)out;   // q region reused as bf16 scratch
  float* dpS      = out + 8388608;                // dp rows; bf16 logits in-slot
  unsigned short* S16 = (unsigned short*)dpS;     // row stride 4096 ushorts (8KB)
  float* out_emb  = out + 41943043;
  float* out_N    = out + 42991619;
  float* out_zav  = out + 42993667;

  hipMemsetAsync(ws + 37068800, 0, 4202496, stream);   // enc_sum + n_total

  k_cbnorm   <<<KC, 256, 0, stream>>>(emb, cb_bf, csq);
  k_transpose<<<dim3(16, 32, 16), 256, 0, stream>>>(z, flatT);
  k_rownorm  <<<NROW, 256, 0, stream>>>(flatT, rnorm, z_bf);
  k_gemm     <<<dim3(NROW / 128, KC / 128), 256, 0, stream>>>(z_bf, cb_bf, csq, S16);
  k_softmax  <<<NROW, 256, 0, stream>>>(dpS, cand_cnt, cand_list);
  k_fixup    <<<NROW, 256, 0, stream>>>(flatT, emb, dpS, cand_cnt, cand_list, idx);
  k_stats    <<<NROW, 256, 0, stream>>>(flatT, rnorm, idx, enc_sum, n_total, cl_part);
  k_tail     <<<KC, 256, 0, stream>>>(za, enc_sum, Nb, n_total, out_zav, out_N, out_emb, cbs_part);
  k_q        <<<32769, 256, 0, stream>>>(flatT, rnorm, idx, out, cl_part, cbs_part);
}

// Round 6
// 393.203 us; speedup vs baseline: 10.6770x; 1.0376x over previous
//
#include <hip/hip_runtime.h>

// Problem constants
#define NROW 16384   // B*H*W
#define KC   2048    // n_codes
#define DIM  512     // embedding dim

typedef __attribute__((ext_vector_type(8))) short  short8;
typedef __attribute__((ext_vector_type(4))) float  floatx4;

// ---------------- helpers ----------------

__device__ __forceinline__ unsigned short f2bf(float f) {
  // round-to-nearest-even fp32 -> bf16 (finite values)
  unsigned int u = __float_as_uint(f);
  u += 0x7fffu + ((u >> 16) & 1u);
  return (unsigned short)(u >> 16);
}

// ---------------- K1: codebook row-normalize -> bf16 + csq ----------------
__global__ void k_cbnorm(const float* __restrict__ emb,
                         unsigned short* __restrict__ cb_bf,
                         float* __restrict__ csq) {
  const int k = blockIdx.x;
  const int t = threadIdx.x;        // 256
  const float* row = emb + (size_t)k * DIM;
  float v0 = row[t], v1 = row[t + 256];
  float ss = v0 * v0 + v1 * v1;
#pragma unroll
  for (int o = 32; o; o >>= 1) ss += __shfl_xor(ss, o, 64);
  __shared__ float red[4];
  if ((t & 63) == 0) red[t >> 6] = ss;
  __syncthreads();
  float tot = red[0] + red[1] + red[2] + red[3];
  float r = 1.0f / fmaxf(sqrtf(tot), 1e-12f);
  cb_bf[(size_t)k * DIM + t]       = f2bf(v0 * r);
  cb_bf[(size_t)k * DIM + t + 256] = f2bf(v1 * r);
  if (t == 0) csq[k] = tot * r * r;   // sum of squares of normalized row (~1)
}

// ---------------- K2: transpose z [B,D,HW] -> flatT [N,D] ----------------
__global__ void k_transpose(const float* __restrict__ z, float* __restrict__ flatT) {
  __shared__ float tile[32][33];
  const int dt = blockIdx.x;   // 0..15  (D/32)
  const int pt = blockIdx.y;   // 0..31  (HW/32)
  const int b  = blockIdx.z;   // 0..15
  const int tx = threadIdx.x & 31;
  const int ty = threadIdx.x >> 5;     // 0..7
  const size_t zb = (size_t)b * (DIM * 1024);
#pragma unroll
  for (int i = 0; i < 4; ++i) {
    int d = dt * 32 + ty + i * 8;
    int p = pt * 32 + tx;
    tile[ty + i * 8][tx] = z[zb + (size_t)d * 1024 + p];
  }
  __syncthreads();
#pragma unroll
  for (int i = 0; i < 4; ++i) {
    int p = pt * 32 + ty + i * 8;
    int d = dt * 32 + tx;
    flatT[(size_t)(b * 1024 + p) * DIM + d] = tile[tx][ty + i * 8];
  }
}

// ---------------- K3: z row norms + bf16 copy ----------------
__global__ void k_rownorm(const float* __restrict__ flatT,
                          float* __restrict__ rnorm,
                          unsigned short* __restrict__ zbf) {
  const int n = blockIdx.x;
  const int t = threadIdx.x;   // 256
  const float* row = flatT + (size_t)n * DIM;
  float v0 = row[t], v1 = row[t + 256];
  float ss = v0 * v0 + v1 * v1;
#pragma unroll
  for (int o = 32; o; o >>= 1) ss += __shfl_xor(ss, o, 64);
  __shared__ float red[4];
  if ((t & 63) == 0) red[t >> 6] = ss;
  __syncthreads();
  float tot = red[0] + red[1] + red[2] + red[3];
  float r = 1.0f / fmaxf(sqrtf(tot), 1e-12f);
  if (t == 0) rnorm[n] = r;
  zbf[(size_t)n * DIM + t]       = f2bf(v0 * r);
  zbf[(size_t)n * DIM + t + 256] = f2bf(v1 * r);
}

// ---------------- K4: bf16 MFMA GEMM -> bf16 logits t = 2*S - csq ----------------
// 128x128 tile, BK=64, 4 waves of 64x64, 16x16x32 MFMA, XOR-swizzled LDS.
// Output: bf16 t for row n stored in the first 4KB of dp row n's 8KB slot
// (row stride 4096 ushorts); halves S write + softmax read traffic.
__global__ __launch_bounds__(256) void k_gemm(const unsigned short* __restrict__ A,
                                              const unsigned short* __restrict__ Bm,
                                              const float* __restrict__ csq,
                                              unsigned short* __restrict__ T16) {
  __shared__ alignas(16) unsigned short smA[128 * 64];
  __shared__ alignas(16) unsigned short smB[128 * 64];
  const int tid  = threadIdx.x;
  const int wid  = tid >> 6;
  const int lane = tid & 63;
  const int m0 = blockIdx.x * 128;
  const int n0 = blockIdx.y * 128;
  const int wm = (wid >> 1) * 64;
  const int wn = (wid & 1) * 64;

  floatx4 acc[4][4];
  const floatx4 z4 = {0.f, 0.f, 0.f, 0.f};
#pragma unroll
  for (int mi = 0; mi < 4; ++mi)
#pragma unroll
    for (int ni = 0; ni < 4; ++ni) acc[mi][ni] = z4;

  const int srow_l = tid >> 3;  // +i*32 per staging issue
  const int spb    = tid & 7;

  for (int kt = 0; kt < 8; ++kt) {
    const int kbase = kt * 64;
    // stage A and B tiles (manual vectorized staging, swizzled layout:
    // physical 16B-block pb holds logical block lb = pb ^ (row & 7))
#pragma unroll
    for (int i = 0; i < 4; ++i) {
      int row = i * 32 + srow_l;
      int lb  = spb ^ (row & 7);
      const short8 va = *(const short8*)(A  + (size_t)(m0 + row) * DIM + kbase + lb * 8);
      const short8 vb = *(const short8*)(Bm + (size_t)(n0 + row) * DIM + kbase + lb * 8);
      *(short8*)&smA[i * 2048 + tid * 8] = va;
      *(short8*)&smB[i * 2048 + tid * 8] = vb;
    }
    __syncthreads();
#pragma unroll
    for (int kk = 0; kk < 2; ++kk) {
      const int q   = lane >> 4;
      const int mr  = lane & 15;
      const int lbq = kk * 4 + q;   // logical 8-elem block index in row
      short8 af[4], bfr[4];
#pragma unroll
      for (int mi = 0; mi < 4; ++mi) {
        int row = wm + mi * 16 + mr;
        int pb  = lbq ^ (row & 7);
        af[mi] = *(const short8*)&smA[row * 64 + pb * 8];
      }
#pragma unroll
      for (int ni = 0; ni < 4; ++ni) {
        int row = wn + ni * 16 + mr;
        int pb  = lbq ^ (row & 7);
        bfr[ni] = *(const short8*)&smB[row * 64 + pb * 8];
      }
#pragma unroll
      for (int mi = 0; mi < 4; ++mi)
#pragma unroll
        for (int ni = 0; ni < 4; ++ni)
          acc[mi][ni] = __builtin_amdgcn_mfma_f32_16x16x32_bf16(af[mi], bfr[ni], acc[mi][ni], 0, 0, 0);
    }
    __syncthreads();
  }

  // epilogue: C/D layout col = lane&15, row = (lane>>4)*4 + reg; t = 2S - csq -> bf16
  const int col = lane & 15;
  const int rq  = (lane >> 4) * 4;
  float csqv[4];
#pragma unroll
  for (int ni = 0; ni < 4; ++ni) csqv[ni] = csq[n0 + wn + ni * 16 + col];
#pragma unroll
  for (int mi = 0; mi < 4; ++mi)
#pragma unroll
    for (int r = 0; r < 4; ++r) {
      size_t rowoff = (size_t)(m0 + wm + mi * 16 + rq + r) * 4096;  // 8KB slot
#pragma unroll
      for (int ni = 0; ni < 4; ++ni)
        T16[rowoff + n0 + wn + ni * 16 + col] = f2bf(2.0f * acc[mi][ni][r] - csqv[ni]);
    }
}

// ---------------- K5: fused softmax + exact fp64 argmin (one pass per row) ----------
// t <= ~1.03 bounded (unit vectors) => fixed reference: dp = exp(t-1)/sum == softmax(t).
// Margin covers bf16-dot (~1e-2/side) + bf16-logit-store quantization (~2e-3/side).
// Candidate set uncapped to 256 LDS slots (typ. 1-5); >256 -> full-KC scan (unreachable).
// fp64 score expression identical to previous rounds -> same winners, same tie-breaks.
#define EXP_MARGIN 0.97531f   // exp(-0.025)

__global__ void k_smfix(float* __restrict__ dp, const float* __restrict__ flatT,
                        const float* __restrict__ emb, int* __restrict__ idx) {
  const int n = blockIdx.x;
  const int t = threadIdx.x;  // 256
  const int lane = t & 63, w = t >> 6;
  float* row = dp + (size_t)n * KC;                      // 8KB slot, fp32 view
  const unsigned short* srow = (const unsigned short*)row;  // bf16 t in first 4KB
  short8 v = *(const short8*)&srow[t * 8];               // k = t*8 .. t*8+7
  float ev[8];
  float mx = 0.f, sum = 0.f;
#pragma unroll
  for (int j = 0; j < 8; ++j) {
    float tv = __uint_as_float(((unsigned)(unsigned short)v[j]) << 16);
    ev[j] = __expf(tv - 1.0f);
    mx = fmaxf(mx, ev[j]);
    sum += ev[j];
  }
#pragma unroll
  for (int o = 32; o; o >>= 1) {
    mx  = fmaxf(mx, __shfl_xor(mx, o, 64));
    sum += __shfl_xor(sum, o, 64);
  }
  __shared__ float  redm[4], reds[4];
  __shared__ int    s_cnt;
  __shared__ int    s_cand[256];
  __shared__ double s_best[4];
  __shared__ int    s_bestk[4];
  if (t == 0) s_cnt = 0;
  if (lane == 0) { redm[w] = mx; reds[w] = sum; }
  __syncthreads();   // orders: all bf16 loads complete before any fp32 store below
  const float EMX = fmaxf(fmaxf(redm[0], redm[1]), fmaxf(redm[2], redm[3]));
  const float inv = 1.0f / (reds[0] + reds[1] + reds[2] + reds[3]);
  const float thr = EMX * EXP_MARGIN;
#pragma unroll
  for (int j = 0; j < 8; ++j) {
    if (ev[j] >= thr) {
      int p = atomicAdd(&s_cnt, 1);
      if (p < 256) s_cand[p] = t * 8 + j;
    }
  }
  floatx4 w0, w1;
#pragma unroll
  for (int j = 0; j < 4; ++j) { w0[j] = ev[j] * inv; w1[j] = ev[j + 4] * inv; }
  *(floatx4*)&row[t * 8]     = w0;
  *(floatx4*)&row[t * 8 + 4] = w1;
  __syncthreads();   // s_cnt / s_cand final
  const int m = s_cnt;
  if (m == 1) {
    if (t == 0) idx[n] = s_cand[0];
    return;
  }

  // ---- exact fp64 argmin among candidates (wave-parallel across 4 waves) ----
  const float* zr = flatT + (size_t)n * DIM;
  float zf[8];
#pragma unroll
  for (int u = 0; u < 8; ++u) zf[u] = zr[lane + 64 * u];
  double zs = 0.0;
#pragma unroll
  for (int u = 0; u < 8; ++u) { double zv = zf[u]; zs += zv * zv; }
#pragma unroll
  for (int o = 32; o; o >>= 1) zs += __shfl_xor(zs, o, 64);
  const double zn = fmax(sqrt(zs), 1e-12);

  double best = 1e300;
  int bestk = 0x7fffffff;
  const int M = (m > 256) ? KC : m;
  for (int ci = w; ci < M; ci += 4) {       // wave-parallel over candidates
    const int k = (m > 256) ? ci : s_cand[ci];
    const float* er = emb + (size_t)k * DIM;
    float ef[8];
#pragma unroll
    for (int u = 0; u < 8; ++u) ef[u] = er[lane + 64 * u];   // 8 independent loads
    double cs = 0.0, dot = 0.0;
#pragma unroll
    for (int u = 0; u < 8; ++u) { double e = ef[u]; double zv = zf[u]; cs += e * e; dot += zv * e; }
#pragma unroll
    for (int o = 32; o; o >>= 1) { cs += __shfl_xor(cs, o, 64); dot += __shfl_xor(dot, o, 64); }
    double cn = fmax(sqrt(cs), 1e-12);
    double score = cs / (cn * cn) - 2.0 * dot / (zn * cn);  // distance minus row-const zsq
    if (score < best || (score == best && k < bestk)) { best = score; bestk = k; }
  }
  if (lane == 0) { s_best[w] = best; s_bestk[w] = bestk; }
  __syncthreads();
  if (t == 0) {
    double b = s_best[0]; int bk = s_bestk[0];
#pragma unroll
    for (int i = 1; i < 4; ++i)
      if (s_best[i] < b || (s_best[i] == b && s_bestk[i] < bk)) { b = s_best[i]; bk = s_bestk[i]; }
    idx[n] = bk;
  }
}

// ---------------- K6: commitment-loss partials + EMA stats (atomics) ----------------
__global__ void k_stats(const float* __restrict__ flatT, const float* __restrict__ rnorm,
                        const int* __restrict__ idx, float* __restrict__ enc_sum,
                        float* __restrict__ n_total, double* __restrict__ cl_part) {
  const int n = blockIdx.x;
  const int t = threadIdx.x;  // 256
  const int j = idx[n];
  const float rn = rnorm[n], rj = rnorm[j];
  const float* zr  = flatT + (size_t)n * DIM;
  const float* zjr = flatT + (size_t)j * DIM;
  double cl = 0.0;
#pragma unroll
  for (int i = 0; i < 2; ++i) {
    int d = t + i * 256;
    float zv = zr[d] * rn;
    float evv = zjr[d] * rj;
    float df = zv - evv;
    cl += (double)df * (double)df;
    atomicAdd(&enc_sum[(size_t)j * DIM + d], zv);
  }
#pragma unroll
  for (int o = 32; o; o >>= 1) cl += __shfl_xor(cl, o, 64);
  __shared__ double red[4];
  if ((t & 63) == 0) red[t >> 6] = cl;
  __syncthreads();
  if (t == 0) {
    cl_part[n] = red[0] + red[1] + red[2] + red[3];
    atomicAdd(&n_total[j], 1.0f);
  }
}

// ---------------- K7: fused tail — z_avg_new, N_new, embeddings_new, |.| partials ----
__global__ void k_tail(const float* __restrict__ za, const float* __restrict__ es,
                       const float* __restrict__ Nb, const float* __restrict__ ntot,
                       float* __restrict__ out_zav, float* __restrict__ outN,
                       float* __restrict__ out_emb, double* __restrict__ cbs_part) {
  const int k = blockIdx.x;   // 2048
  const int t = threadIdx.x;  // 256
  const int lane = t & 63, wid = t >> 6;
  float s = 0.f;
#pragma unroll
  for (int i = 0; i < 8; ++i) {
    int kk = t + i * 256;
    s += 0.99f * Nb[kk] + 0.01f * ntot[kk];
  }
#pragma unroll
  for (int o = 32; o; o >>= 1) s += __shfl_xor(s, o, 64);
  __shared__ float redn[4];
  if (lane == 0) redn[wid] = s;
  __syncthreads();
  const float nv = redn[0] + redn[1] + redn[2] + redn[3];
  const float Nn = 0.99f * Nb[k] + 0.01f * ntot[k];
  if (t == 0) outN[k] = Nn;
  const float w = (Nn + 1e-5f) / (nv + 0.02048f) * nv;
  double a = 0.0;
#pragma unroll
  for (int i = 0; i < 2; ++i) {
    size_t gi = (size_t)k * DIM + t + i * 256;
    float zv = 0.99f * za[gi] + 0.01f * es[gi];
    out_zav[gi] = zv;
    float e = zv / w;
    out_emb[gi] = e;
    a += (double)fabsf(e);
  }
#pragma unroll
  for (int o = 32; o; o >>= 1) a += __shfl_xor(a, o, 64);
  __shared__ double red[4];
  if (lane == 0) red[wid] = a;
  __syncthreads();
  if (t == 0) cbs_part[k] = red[0] + red[1] + red[2] + red[3];
}

// ---------------- K8: q gather + (extra block) final scalar reductions ----------------
__global__ void k_q(const float* __restrict__ flatT, const float* __restrict__ rnorm,
                    const int* __restrict__ idx, float* __restrict__ out,
                    const double* __restrict__ cl_part, const double* __restrict__ cbs_part) {
  if (blockIdx.x == 32768) {
    const int t = threadIdx.x;  // 256
    double cl = 0.0, cb = 0.0;
    for (int i = t; i < NROW; i += 256) cl += cl_part[i];
    for (int i = t; i < KC; i += 256) cb += cbs_part[i];
#pragma unroll
    for (int o = 32; o; o >>= 1) { cl += __shfl_xor(cl, o, 64); cb += __shfl_xor(cb, o, 64); }
    __shared__ double redc[4], redb[4];
    if ((t & 63) == 0) { redc[t >> 6] = cl; redb[t >> 6] = cb; }
    __syncthreads();
    if (t == 0) {
      double clm = (redc[0] + redc[1] + redc[2] + redc[3]) / 8388608.0;  // N*D
      double cbs = redb[0] + redb[1] + redb[2] + redb[3];
      out[41943040] = (float)clm;          // commitment_loss
      out[41943041] = (float)(0.25 * clm); // loss = BETA * commitment_loss
      out[41943042] = (float)cbs;          // codebook_sum
    }
    return;
  }
  const int o = blockIdx.x * 256 + threadIdx.x;
  const int b = o >> 19;            // D*H*W = 2^19
  const int d = (o >> 10) & 511;
  const int p = o & 1023;
  const int j = idx[(b << 10) + p];
  out[o] = flatT[(size_t)j * DIM + d] * rnorm[j];
}

// ---------------- launcher ----------------
extern "C" void kernel_launch(void* const* d_in, const int* in_sizes, int n_in,
                              void* d_out, int out_size, void* d_ws, size_t ws_size,
                              hipStream_t stream) {
  const float* z   = (const float*)d_in[0];
  const float* emb = (const float*)d_in[1];
  const float* Nb  = (const float*)d_in[2];
  const float* za  = (const float*)d_in[3];
  float* out = (float*)d_out;
  char*  ws  = (char*)d_ws;

  // workspace layout (bytes)
  float*          flatT     = (float*)(ws + 0);          // 33554432
  unsigned short* cb_bf     = (unsigned short*)(ws + 33554432); // 2097152
  float*          csq       = (float*)(ws + 35651584);   // 8192
  float*          rnorm     = (float*)(ws + 35659776);   // 65536
  int*            idx       = (int*)(ws + 35725312);     // 65536
  double*         cl_part   = (double*)(ws + 36904960);  // 131072
  double*         cbs_part  = (double*)(ws + 37036032);  // 32768 (2048 used)
  float*          enc_sum   = (float*)(ws + 37068800);   // 4194304 (zeroed)
  float*          n_total   = (float*)(ws + 41263104);   // 8192    (zeroed)

  // d_out regions (floats): q[0..8388608), dp[8388608..41943040),
  // scalars[41943040..3), emb_new[41943043), N_new[42991619), z_avg_new[42993667)
  unsigned short* z_bf  = (unsigned short*)out;   // q region reused as bf16 scratch
  float* dpS      = out + 8388608;                // dp rows; bf16 logits in-slot
  unsigned short* S16 = (unsigned short*)dpS;     // row stride 4096 ushorts (8KB)
  float* out_emb  = out + 41943043;
  float* out_N    = out + 42991619;
  float* out_zav  = out + 42993667;

  hipMemsetAsync(ws + 37068800, 0, 4202496, stream);   // enc_sum + n_total

  k_cbnorm   <<<KC, 256, 0, stream>>>(emb, cb_bf, csq);
  k_transpose<<<dim3(16, 32, 16), 256, 0, stream>>>(z, flatT);
  k_rownorm  <<<NROW, 256, 0, stream>>>(flatT, rnorm, z_bf);
  k_gemm     <<<dim3(NROW / 128, KC / 128), 256, 0, stream>>>(z_bf, cb_bf, csq, S16);
  k_smfix    <<<NROW, 256, 0, stream>>>(dpS, flatT, emb, idx);
  k_stats    <<<NROW, 256, 0, stream>>>(flatT, rnorm, idx, enc_sum, n_total, cl_part);
  k_tail     <<<KC, 256, 0, stream>>>(za, enc_sum, Nb, n_total, out_zav, out_N, out_emb, cbs_part);
  k_q        <<<32769, 256, 0, stream>>>(flatT, rnorm, idx, out, cl_part, cbs_part);
}

// Round 7
// 382.599 us; speedup vs baseline: 10.9730x; 1.0277x over previous
//
#include <hip/hip_runtime.h>

// Problem constants
#define NROW 16384   // B*H*W
#define KC   2048    // n_codes
#define DIM  512     // embedding dim

typedef __attribute__((ext_vector_type(8))) short  short8;
typedef __attribute__((ext_vector_type(4))) float  floatx4;

// ---------------- helpers ----------------

__device__ __forceinline__ unsigned short f2bf(float f) {
  // round-to-nearest-even fp32 -> bf16 (finite values)
  unsigned int u = __float_as_uint(f);
  u += 0x7fffu + ((u >> 16) & 1u);
  return (unsigned short)(u >> 16);
}

// async global->LDS, 16B per lane. HW semantics: LDS dest = wave-uniform base
// + lane*16; our per-lane dest (&sm[i*2048 + tid*8]) coincides with that.
// Global SOURCE is per-lane -> swizzled layout achieved by pre-swizzling the
// source column block (rule: linear dest + inverse-swz source + swz read).
#define GLDS(gsrc, ldst) __builtin_amdgcn_global_load_lds( \
    (const __attribute__((address_space(1))) unsigned int*)(gsrc), \
    (__attribute__((address_space(3))) unsigned int*)(ldst), 16, 0, 0)

// ---------------- K1: codebook row-normalize -> bf16 + csq ----------------
__global__ void k_cbnorm(const float* __restrict__ emb,
                         unsigned short* __restrict__ cb_bf,
                         float* __restrict__ csq) {
  const int k = blockIdx.x;
  const int t = threadIdx.x;        // 256
  const float* row = emb + (size_t)k * DIM;
  float v0 = row[t], v1 = row[t + 256];
  float ss = v0 * v0 + v1 * v1;
#pragma unroll
  for (int o = 32; o; o >>= 1) ss += __shfl_xor(ss, o, 64);
  __shared__ float red[4];
  if ((t & 63) == 0) red[t >> 6] = ss;
  __syncthreads();
  float tot = red[0] + red[1] + red[2] + red[3];
  float r = 1.0f / fmaxf(sqrtf(tot), 1e-12f);
  cb_bf[(size_t)k * DIM + t]       = f2bf(v0 * r);
  cb_bf[(size_t)k * DIM + t + 256] = f2bf(v1 * r);
  if (t == 0) csq[k] = tot * r * r;   // sum of squares of normalized row (~1)
}

// ---------------- K2: transpose z [B,D,HW] -> flatT [N,D] ----------------
__global__ void k_transpose(const float* __restrict__ z, float* __restrict__ flatT) {
  __shared__ float tile[32][33];
  const int dt = blockIdx.x;   // 0..15  (D/32)
  const int pt = blockIdx.y;   // 0..31  (HW/32)
  const int b  = blockIdx.z;   // 0..15
  const int tx = threadIdx.x & 31;
  const int ty = threadIdx.x >> 5;     // 0..7
  const size_t zb = (size_t)b * (DIM * 1024);
#pragma unroll
  for (int i = 0; i < 4; ++i) {
    int d = dt * 32 + ty + i * 8;
    int p = pt * 32 + tx;
    tile[ty + i * 8][tx] = z[zb + (size_t)d * 1024 + p];
  }
  __syncthreads();
#pragma unroll
  for (int i = 0; i < 4; ++i) {
    int p = pt * 32 + ty + i * 8;
    int d = dt * 32 + tx;
    flatT[(size_t)(b * 1024 + p) * DIM + d] = tile[tx][ty + i * 8];
  }
}

// ---------------- K3: z row norms + bf16 copy ----------------
__global__ void k_rownorm(const float* __restrict__ flatT,
                          float* __restrict__ rnorm,
                          unsigned short* __restrict__ zbf) {
  const int n = blockIdx.x;
  const int t = threadIdx.x;   // 256
  const float* row = flatT + (size_t)n * DIM;
  float v0 = row[t], v1 = row[t + 256];
  float ss = v0 * v0 + v1 * v1;
#pragma unroll
  for (int o = 32; o; o >>= 1) ss += __shfl_xor(ss, o, 64);
  __shared__ float red[4];
  if ((t & 63) == 0) red[t >> 6] = ss;
  __syncthreads();
  float tot = red[0] + red[1] + red[2] + red[3];
  float r = 1.0f / fmaxf(sqrtf(tot), 1e-12f);
  if (t == 0) rnorm[n] = r;
  zbf[(size_t)n * DIM + t]       = f2bf(v0 * r);
  zbf[(size_t)n * DIM + t + 256] = f2bf(v1 * r);
}

// ---------------- K4: bf16 MFMA GEMM -> bf16 logits t = 2*S - csq ----------------
// 128x128 tile, BK=64, 4 waves of 64x64, 16x16x32 MFMA, XOR-swizzled LDS.
// Staging via global_load_lds (16B/lane): LDS dest linear (base + lane*16),
// swizzle realized by pre-swizzling the per-lane GLOBAL source column block
// (lb = pb ^ (row&7)); read path identical to the reg-staged version.
__global__ __launch_bounds__(256) void k_gemm(const unsigned short* __restrict__ A,
                                              const unsigned short* __restrict__ Bm,
                                              const float* __restrict__ csq,
                                              unsigned short* __restrict__ T16) {
  __shared__ alignas(16) unsigned short smA[128 * 64];
  __shared__ alignas(16) unsigned short smB[128 * 64];
  const int tid  = threadIdx.x;
  const int wid  = tid >> 6;
  const int lane = tid & 63;
  const int m0 = blockIdx.x * 128;
  const int n0 = blockIdx.y * 128;
  const int wm = (wid >> 1) * 64;
  const int wn = (wid & 1) * 64;

  floatx4 acc[4][4];
  const floatx4 z4 = {0.f, 0.f, 0.f, 0.f};
#pragma unroll
  for (int mi = 0; mi < 4; ++mi)
#pragma unroll
    for (int ni = 0; ni < 4; ++ni) acc[mi][ni] = z4;

  const int srow_l = tid >> 3;  // +i*32 per staging issue
  const int spb    = tid & 7;   // physical 16B block this lane fills
  // swizzled source: physical block pb holds logical block lb = pb ^ (row & 7)
  const int srow0 = srow_l;
  const int slb0  = spb ^ (srow_l & 7);   // (row&7) == (srow_l&7) since i*32 ≡ 0 (mod 8)
  const unsigned short* Abase = A  + (size_t)(m0 + srow0) * DIM + slb0 * 8;
  const unsigned short* Bbase = Bm + (size_t)(n0 + srow0) * DIM + slb0 * 8;

  for (int kt = 0; kt < 8; ++kt) {
    const int kbase = kt * 64;
#pragma unroll
    for (int i = 0; i < 4; ++i) {
      GLDS(Abase + (size_t)i * 32 * DIM + kbase, &smA[i * 2048 + tid * 8]);
      GLDS(Bbase + (size_t)i * 32 * DIM + kbase, &smB[i * 2048 + tid * 8]);
    }
    __syncthreads();   // compiler drains vmcnt before s_barrier
#pragma unroll
    for (int kk = 0; kk < 2; ++kk) {
      const int q   = lane >> 4;
      const int mr  = lane & 15;
      const int lbq = kk * 4 + q;   // logical 8-elem block index in row
      short8 af[4], bfr[4];
#pragma unroll
      for (int mi = 0; mi < 4; ++mi) {
        int row = wm + mi * 16 + mr;
        int pb  = lbq ^ (row & 7);
        af[mi] = *(const short8*)&smA[row * 64 + pb * 8];
      }
#pragma unroll
      for (int ni = 0; ni < 4; ++ni) {
        int row = wn + ni * 16 + mr;
        int pb  = lbq ^ (row & 7);
        bfr[ni] = *(const short8*)&smB[row * 64 + pb * 8];
      }
#pragma unroll
      for (int mi = 0; mi < 4; ++mi)
#pragma unroll
        for (int ni = 0; ni < 4; ++ni)
          acc[mi][ni] = __builtin_amdgcn_mfma_f32_16x16x32_bf16(af[mi], bfr[ni], acc[mi][ni], 0, 0, 0);
    }
    __syncthreads();
  }

  // epilogue: C/D layout col = lane&15, row = (lane>>4)*4 + reg; t = 2S - csq -> bf16
  const int col = lane & 15;
  const int rq  = (lane >> 4) * 4;
  float csqv[4];
#pragma unroll
  for (int ni = 0; ni < 4; ++ni) csqv[ni] = csq[n0 + wn + ni * 16 + col];
#pragma unroll
  for (int mi = 0; mi < 4; ++mi)
#pragma unroll
    for (int r = 0; r < 4; ++r) {
      size_t rowoff = (size_t)(m0 + wm + mi * 16 + rq + r) * 4096;  // 8KB slot
#pragma unroll
      for (int ni = 0; ni < 4; ++ni)
        T16[rowoff + n0 + wn + ni * 16 + col] = f2bf(2.0f * acc[mi][ni][r] - csqv[ni]);
    }
}

// ---------------- K5: fused softmax + exact fp64 argmin (one pass per row) ----------
// t <= ~1.03 bounded (unit vectors) => fixed reference: dp = exp(t-1)/sum == softmax(t).
// Margin covers bf16-dot (~1e-2/side) + bf16-logit-store quantization (~2e-3/side).
// Candidate set uncapped to 256 LDS slots (typ. 1-5); >256 -> full-KC scan (unreachable).
// fp64 score expression identical to previous rounds -> same winners, same tie-breaks.
#define EXP_MARGIN 0.97531f   // exp(-0.025)

__global__ void k_smfix(float* __restrict__ dp, const float* __restrict__ flatT,
                        const float* __restrict__ emb, int* __restrict__ idx) {
  const int n = blockIdx.x;
  const int t = threadIdx.x;  // 256
  const int lane = t & 63, w = t >> 6;
  float* row = dp + (size_t)n * KC;                      // 8KB slot, fp32 view
  const unsigned short* srow = (const unsigned short*)row;  // bf16 t in first 4KB
  short8 v = *(const short8*)&srow[t * 8];               // k = t*8 .. t*8+7
  float ev[8];
  float mx = 0.f, sum = 0.f;
#pragma unroll
  for (int j = 0; j < 8; ++j) {
    float tv = __uint_as_float(((unsigned)(unsigned short)v[j]) << 16);
    ev[j] = __expf(tv - 1.0f);
    mx = fmaxf(mx, ev[j]);
    sum += ev[j];
  }
#pragma unroll
  for (int o = 32; o; o >>= 1) {
    mx  = fmaxf(mx, __shfl_xor(mx, o, 64));
    sum += __shfl_xor(sum, o, 64);
  }
  __shared__ float  redm[4], reds[4];
  __shared__ int    s_cnt;
  __shared__ int    s_cand[256];
  __shared__ double s_best[4];
  __shared__ int    s_bestk[4];
  if (t == 0) s_cnt = 0;
  if (lane == 0) { redm[w] = mx; reds[w] = sum; }
  __syncthreads();   // orders: all bf16 loads complete before any fp32 store below
  const float EMX = fmaxf(fmaxf(redm[0], redm[1]), fmaxf(redm[2], redm[3]));
  const float inv = 1.0f / (reds[0] + reds[1] + reds[2] + reds[3]);
  const float thr = EMX * EXP_MARGIN;
#pragma unroll
  for (int j = 0; j < 8; ++j) {
    if (ev[j] >= thr) {
      int p = atomicAdd(&s_cnt, 1);
      if (p < 256) s_cand[p] = t * 8 + j;
    }
  }
  floatx4 w0, w1;
#pragma unroll
  for (int j = 0; j < 4; ++j) { w0[j] = ev[j] * inv; w1[j] = ev[j + 4] * inv; }
  *(floatx4*)&row[t * 8]     = w0;
  *(floatx4*)&row[t * 8 + 4] = w1;
  __syncthreads();   // s_cnt / s_cand final
  const int m = s_cnt;
  if (m == 1) {
    if (t == 0) idx[n] = s_cand[0];
    return;
  }

  // ---- exact fp64 argmin among candidates (wave-parallel across 4 waves) ----
  const float* zr = flatT + (size_t)n * DIM;
  float zf[8];
#pragma unroll
  for (int u = 0; u < 8; ++u) zf[u] = zr[lane + 64 * u];
  double zs = 0.0;
#pragma unroll
  for (int u = 0; u < 8; ++u) { double zv = zf[u]; zs += zv * zv; }
#pragma unroll
  for (int o = 32; o; o >>= 1) zs += __shfl_xor(zs, o, 64);
  const double zn = fmax(sqrt(zs), 1e-12);

  double best = 1e300;
  int bestk = 0x7fffffff;
  const int M = (m > 256) ? KC : m;
  for (int ci = w; ci < M; ci += 4) {       // wave-parallel over candidates
    const int k = (m > 256) ? ci : s_cand[ci];
    const float* er = emb + (size_t)k * DIM;
    float ef[8];
#pragma unroll
    for (int u = 0; u < 8; ++u) ef[u] = er[lane + 64 * u];   // 8 independent loads
    double cs = 0.0, dot = 0.0;
#pragma unroll
    for (int u = 0; u < 8; ++u) { double e = ef[u]; double zv = zf[u]; cs += e * e; dot += zv * e; }
#pragma unroll
    for (int o = 32; o; o >>= 1) { cs += __shfl_xor(cs, o, 64); dot += __shfl_xor(dot, o, 64); }
    double cn = fmax(sqrt(cs), 1e-12);
    double score = cs / (cn * cn) - 2.0 * dot / (zn * cn);  // distance minus row-const zsq
    if (score < best || (score == best && k < bestk)) { best = score; bestk = k; }
  }
  if (lane == 0) { s_best[w] = best; s_bestk[w] = bestk; }
  __syncthreads();
  if (t == 0) {
    double b = s_best[0]; int bk = s_bestk[0];
#pragma unroll
    for (int i = 1; i < 4; ++i)
      if (s_best[i] < b || (s_best[i] == b && s_bestk[i] < bk)) { b = s_best[i]; bk = s_bestk[i]; }
    idx[n] = bk;
  }
}

// ---------------- K6: commitment-loss partials + EMA stats (atomics) ----------------
__global__ void k_stats(const float* __restrict__ flatT, const float* __restrict__ rnorm,
                        const int* __restrict__ idx, float* __restrict__ enc_sum,
                        float* __restrict__ n_total, double* __restrict__ cl_part) {
  const int n = blockIdx.x;
  const int t = threadIdx.x;  // 256
  const int j = idx[n];
  const float rn = rnorm[n], rj = rnorm[j];
  const float* zr  = flatT + (size_t)n * DIM;
  const float* zjr = flatT + (size_t)j * DIM;
  double cl = 0.0;
#pragma unroll
  for (int i = 0; i < 2; ++i) {
    int d = t + i * 256;
    float zv = zr[d] * rn;
    float evv = zjr[d] * rj;
    float df = zv - evv;
    cl += (double)df * (double)df;
    atomicAdd(&enc_sum[(size_t)j * DIM + d], zv);
  }
#pragma unroll
  for (int o = 32; o; o >>= 1) cl += __shfl_xor(cl, o, 64);
  __shared__ double red[4];
  if ((t & 63) == 0) red[t >> 6] = cl;
  __syncthreads();
  if (t == 0) {
    cl_part[n] = red[0] + red[1] + red[2] + red[3];
    atomicAdd(&n_total[j], 1.0f);
  }
}

// ---------------- K7: fused tail — z_avg_new, N_new, embeddings_new, |.| partials ----
__global__ void k_tail(const float* __restrict__ za, const float* __restrict__ es,
                       const float* __restrict__ Nb, const float* __restrict__ ntot,
                       float* __restrict__ out_zav, float* __restrict__ outN,
                       float* __restrict__ out_emb, double* __restrict__ cbs_part) {
  const int k = blockIdx.x;   // 2048
  const int t = threadIdx.x;  // 256
  const int lane = t & 63, wid = t >> 6;
  float s = 0.f;
#pragma unroll
  for (int i = 0; i < 8; ++i) {
    int kk = t + i * 256;
    s += 0.99f * Nb[kk] + 0.01f * ntot[kk];
  }
#pragma unroll
  for (int o = 32; o; o >>= 1) s += __shfl_xor(s, o, 64);
  __shared__ float redn[4];
  if (lane == 0) redn[wid] = s;
  __syncthreads();
  const float nv = redn[0] + redn[1] + redn[2] + redn[3];
  const float Nn = 0.99f * Nb[k] + 0.01f * ntot[k];
  if (t == 0) outN[k] = Nn;
  const float w = (Nn + 1e-5f) / (nv + 0.02048f) * nv;
  double a = 0.0;
#pragma unroll
  for (int i = 0; i < 2; ++i) {
    size_t gi = (size_t)k * DIM + t + i * 256;
    float zv = 0.99f * za[gi] + 0.01f * es[gi];
    out_zav[gi] = zv;
    float e = zv / w;
    out_emb[gi] = e;
    a += (double)fabsf(e);
  }
#pragma unroll
  for (int o = 32; o; o >>= 1) a += __shfl_xor(a, o, 64);
  __shared__ double red[4];
  if (lane == 0) red[wid] = a;
  __syncthreads();
  if (t == 0) cbs_part[k] = red[0] + red[1] + red[2] + red[3];
}

// ---------------- K8: q gather + (extra block) final scalar reductions ----------------
__global__ void k_q(const float* __restrict__ flatT, const float* __restrict__ rnorm,
                    const int* __restrict__ idx, float* __restrict__ out,
                    const double* __restrict__ cl_part, const double* __restrict__ cbs_part) {
  if (blockIdx.x == 32768) {
    const int t = threadIdx.x;  // 256
    double cl = 0.0, cb = 0.0;
    for (int i = t; i < NROW; i += 256) cl += cl_part[i];
    for (int i = t; i < KC; i += 256) cb += cbs_part[i];
#pragma unroll
    for (int o = 32; o; o >>= 1) { cl += __shfl_xor(cl, o, 64); cb += __shfl_xor(cb, o, 64); }
    __shared__ double redc[4], redb[4];
    if ((t & 63) == 0) { redc[t >> 6] = cl; redb[t >> 6] = cb; }
    __syncthreads();
    if (t == 0) {
      double clm = (redc[0] + redc[1] + redc[2] + redc[3]) / 8388608.0;  // N*D
      double cbs = redb[0] + redb[1] + redb[2] + redb[3];
      out[41943040] = (float)clm;          // commitment_loss
      out[41943041] = (float)(0.25 * clm); // loss = BETA * commitment_loss
      out[41943042] = (float)cbs;          // codebook_sum
    }
    return;
  }
  const int o = blockIdx.x * 256 + threadIdx.x;
  const int b = o >> 19;            // D*H*W = 2^19
  const int d = (o >> 10) & 511;
  const int p = o & 1023;
  const int j = idx[(b << 10) + p];
  out[o] = flatT[(size_t)j * DIM + d] * rnorm[j];
}

// ---------------- launcher ----------------
extern "C" void kernel_launch(void* const* d_in, const int* in_sizes, int n_in,
                              void* d_out, int out_size, void* d_ws, size_t ws_size,
                              hipStream_t stream) {
  const float* z   = (const float*)d_in[0];
  const float* emb = (const float*)d_in[1];
  const float* Nb  = (const float*)d_in[2];
  const float* za  = (const float*)d_in[3];
  float* out = (float*)d_out;
  char*  ws  = (char*)d_ws;

  // workspace layout (bytes)
  float*          flatT     = (float*)(ws + 0);          // 33554432
  unsigned short* cb_bf     = (unsigned short*)(ws + 33554432); // 2097152
  float*          csq       = (float*)(ws + 35651584);   // 8192
  float*          rnorm     = (float*)(ws + 35659776);   // 65536
  int*            idx       = (int*)(ws + 35725312);     // 65536
  double*         cl_part   = (double*)(ws + 36904960);  // 131072
  double*         cbs_part  = (double*)(ws + 37036032);  // 32768 (2048 used)
  float*          enc_sum   = (float*)(ws + 37068800);   // 4194304 (zeroed)
  float*          n_total   = (float*)(ws + 41263104);   // 8192    (zeroed)

  // d_out regions (floats): q[0..8388608), dp[8388608..41943040),
  // scalars[41943040..3), emb_new[41943043), N_new[42991619), z_avg_new[42993667)
  unsigned short* z_bf  = (unsigned short*)out;   // q region reused as bf16 scratch
  float* dpS      = out + 8388608;                // dp rows; bf16 logits in-slot
  unsigned short* S16 = (unsigned short*)dpS;     // row stride 4096 ushorts (8KB)
  float* out_emb  = out + 41943043;
  float* out_N    = out + 42991619;
  float* out_zav  = out + 42993667;

  hipMemsetAsync(ws + 37068800, 0, 4202496, stream);   // enc_sum + n_total

  k_cbnorm   <<<KC, 256, 0, stream>>>(emb, cb_bf, csq);
  k_transpose<<<dim3(16, 32, 16), 256, 0, stream>>>(z, flatT);
  k_rownorm  <<<NROW, 256, 0, stream>>>(flatT, rnorm, z_bf);
  k_gemm     <<<dim3(NROW / 128, KC / 128), 256, 0, stream>>>(z_bf, cb_bf, csq, S16);
  k_smfix    <<<NROW, 256, 0, stream>>>(dpS, flatT, emb, idx);
  k_stats    <<<NROW, 256, 0, stream>>>(flatT, rnorm, idx, enc_sum, n_total, cl_part);
  k_tail     <<<KC, 256, 0, stream>>>(za, enc_sum, Nb, n_total, out_zav, out_N, out_emb, cbs_part);
  k_q        <<<32769, 256, 0, stream>>>(flatT, rnorm, idx, out, cl_part, cbs_part);
}